// Round 4
// baseline (993.646 us; speedup 1.0000x reference)
//
#include <hip/hip_runtime.h>

typedef unsigned short u16;
typedef __attribute__((ext_vector_type(8))) short bf16x8;
typedef __attribute__((ext_vector_type(4))) float f32x4;
typedef __attribute__((ext_vector_type(16))) float f32x16;
typedef __attribute__((ext_vector_type(4))) int i32x4;

#define M_ROWS 8192
#define N_OUT  14336
#define K_IN   4096
#define NTILE  64   // K_IN / 64

__constant__ float NF4_TAB[16] = {
    -1.0f, -0.6961928009986877f, -0.5250730514526367f, -0.39491748809814453f,
    -0.28444138169288635f, -0.18477343022823334f, -0.09105003625154495f, 0.0f,
    0.07958029955625534f, 0.16093020141124725f, 0.24611230194568634f,
    0.33791524171829224f, 0.44070982933044434f, 0.5626170039176941f,
    0.7229568362236023f, 1.0f};

static __device__ __forceinline__ u16 f2bf(float f) {
  union { float f; unsigned u; } v;
  v.f = f;
  unsigned u = v.u;
  unsigned r = (u + 0x7fffu + ((u >> 16) & 1u)) >> 16;
  return (u16)r;
}

static __device__ __forceinline__ void async_load16(const void* g, void* l) {
  __builtin_amdgcn_global_load_lds(
      (const __attribute__((address_space(1))) void*)g,
      (__attribute__((address_space(3))) void*)l, 16, 0, 0);
}

// ---------------------------------------------------------------------------
// Dequant W: 4 packed int32 / thread -> 8 bf16 (one 16B store)
// ---------------------------------------------------------------------------
__global__ __launch_bounds__(256) void dequant_w_kernel(
    const int* __restrict__ wp, const float* __restrict__ wa,
    u16* __restrict__ wout) {
  int t = blockIdx.x * 256 + threadIdx.x;
  const i32x4 p = __builtin_nontemporal_load(
      reinterpret_cast<const i32x4*>(wp) + t);
  float am = wa[t >> 3];
  int v[4] = {p.x, p.y, p.z, p.w};
  union { u16 us[8]; i32x4 v4; } o;
#pragma unroll
  for (int j = 0; j < 4; ++j) {
    o.us[2 * j]     = f2bf(NF4_TAB[(v[j] >> 4) & 15] * am);
    o.us[2 * j + 1] = f2bf(NF4_TAB[v[j] & 15] * am);
  }
  reinterpret_cast<i32x4*>(wout)[t] = o.v4;
}

// ---------------------------------------------------------------------------
// Convert X fp32 -> bf16, 8 elements/thread
// ---------------------------------------------------------------------------
__global__ __launch_bounds__(256) void convert_x_kernel(
    const float* __restrict__ x, u16* __restrict__ xb) {
  int t = blockIdx.x * 256 + threadIdx.x;
  const f32x4 a = __builtin_nontemporal_load(
      reinterpret_cast<const f32x4*>(x) + 2 * t);
  const f32x4 b = __builtin_nontemporal_load(
      reinterpret_cast<const f32x4*>(x) + 2 * t + 1);
  union { u16 us[8]; i32x4 v4; } o;
  o.us[0] = f2bf(a.x); o.us[1] = f2bf(a.y);
  o.us[2] = f2bf(a.z); o.us[3] = f2bf(a.w);
  o.us[4] = f2bf(b.x); o.us[5] = f2bf(b.y);
  o.us[6] = f2bf(b.z); o.us[7] = f2bf(b.w);
  reinterpret_cast<i32x4*>(xb)[t] = o.v4;
}

// ---------------------------------------------------------------------------
// 256x256x64 8-phase pipelined NT GEMM, 32x32x16 MFMA.
// A[M][K], B[N][K] bf16; C[M][N] fp32 + NF4 bias, non-temporal C stores.
// LDS: 2 buffers x (A 256x64 + B 256x64) bf16 = 128 KiB (dynamic).
// Swizzle: 16B chunk c' = c ^ (row&7) via pre-swizzled global src (linear
// gload_lds dest) + swizzled ds_read offsets (same involution).
// No explicit lgkmcnt: ds_reads are compiler-visible loads -> hipcc inserts
// fine-grained waits, letting early MFMAs overlap the read drain.
// ---------------------------------------------------------------------------
__global__ __launch_bounds__(512, 2) void gemm_nf4_256(
    const u16* __restrict__ A, const u16* __restrict__ B,
    float* __restrict__ C, const int* __restrict__ bp,
    const float* __restrict__ ba) {
  constexpr int K = K_IN, N = N_OUT;
  extern __shared__ u16 smem[];
  u16* sA = smem;            // [2][256][64]
  u16* sB = smem + 32768;    // [2][256][64]

  const int tid = threadIdx.x;
  const int w = tid >> 6, lane = tid & 63;
  const int r32 = lane & 31, hi = lane >> 5;
  const int wr = w >> 2, wc = w & 3;       // 2 x 4 wave grid

  // bijective XCD swizzle (1792 % 8 == 0): contiguous 224-wg chunk per XCD
  int bid = blockIdx.x;
  int cpx = gridDim.x >> 3;
  int wg = (bid & 7) * cpx + (bid >> 3);
  // mt-inner-8 supertile (L2 locality on B panels)
  int grp = wg / 448;                  // 448 = 56*8
  int rem = wg - grp * 448;
  int nt = rem >> 3;
  int mt = grp * 8 + (rem & 7);
  const size_t m0 = (size_t)mt * 256, n0 = (size_t)nt * 256;

  const u16* gA = A + m0 * K;
  const u16* gB = B + n0 * K;

  // read-side swizzled chunk offsets (u16 units), one per 16-wide k-step
  int cswz[4];
#pragma unroll
  for (int ks = 0; ks < 4; ++ks)
    cswz[ks] = ((ks * 2 + hi) ^ (lane & 7)) * 8;
  // stage-side per-lane global chunk (involution partner)
  const int cg = ((lane & 7) ^ (lane >> 3)) * 8;
  const int jlane = lane >> 3;

  f32x16 acc[4][2] = {};       // [m-tile 32][n-tile 32] accumulators
  bf16x8 aF[2][4];             // [m-tile within quadrant][k-step]
  bf16x8 bF[2][4];             // [n-quadrant][k-step]

#define FENCE() asm volatile("" ::: "memory")
#define BAR() do { __builtin_amdgcn_s_barrier(); FENCE(); } while (0)
#define VM(n) asm volatile("s_waitcnt vmcnt(" #n ")" ::: "memory")

#define STAGE_A(u, mq) do {                                                  \
    int P_ = (u) & 1;                                                        \
    _Pragma("unroll")                                                        \
    for (int i_ = 0; i_ < 2; ++i_) {                                         \
      int j0_ = (i_ * 8 + w) * 8;                                            \
      int R0_ = (mq) * 64 + ((j0_ >> 6) << 7) + (j0_ & 63);                  \
      int R_ = R0_ + jlane;                                                  \
      async_load16(gA + (size_t)R_ * K + (u) * 64 + cg,                      \
                   sA + P_ * 16384 + R0_ * 64);                              \
    } } while (0)

#define STAGE_B(u, nq) do {                                                  \
    int P_ = (u) & 1;                                                        \
    _Pragma("unroll")                                                        \
    for (int i_ = 0; i_ < 2; ++i_) {                                         \
      int j0_ = (i_ * 8 + w) * 8;                                            \
      int R0_ = (nq) * 32 + ((j0_ >> 5) << 6) + (j0_ & 31);                  \
      int R_ = R0_ + jlane;                                                  \
      async_load16(gB + (size_t)R_ * K + (u) * 64 + cg,                      \
                   sB + P_ * 16384 + R0_ * 64);                              \
    } } while (0)

  // A-fragments for quadrant mq: rows wr*128 + (2mq+t)*32 + r32
#define READ_A(P, mq) do {                                                   \
    const u16* pa_ = sA + (P) * 16384 + (wr * 128 + (mq) * 64 + r32) * 64;   \
    _Pragma("unroll")                                                        \
    for (int t_ = 0; t_ < 2; ++t_)                                           \
      _Pragma("unroll")                                                      \
      for (int ks_ = 0; ks_ < 4; ++ks_)                                      \
        aF[t_][ks_] = *(const bf16x8*)(pa_ + t_ * 2048 + cswz[ks_]);         \
    } while (0)

  // B-fragments for quadrant nq: rows wc*64 + nq*32 + r32
#define READ_B(P, nq) do {                                                   \
    const u16* pb_ = sB + (P) * 16384 + (wc * 64 + (nq) * 32 + r32) * 64;    \
    _Pragma("unroll")                                                        \
    for (int ks_ = 0; ks_ < 4; ++ks_)                                        \
      bF[(nq)][ks_] = *(const bf16x8*)(pb_ + cswz[ks_]);                     \
    } while (0)

#define MFMA_Q(mq, nq) do {                                                  \
    __builtin_amdgcn_s_setprio(1);                                           \
    _Pragma("unroll")                                                        \
    for (int ks_ = 0; ks_ < 4; ++ks_)                                        \
      _Pragma("unroll")                                                      \
      for (int t_ = 0; t_ < 2; ++t_)                                         \
        acc[(mq) * 2 + t_][(nq)] =                                           \
            __builtin_amdgcn_mfma_f32_32x32x16_bf16(                         \
                aF[t_][ks_], bF[(nq)][ks_], acc[(mq) * 2 + t_][(nq)],        \
                0, 0, 0);                                                    \
    __builtin_amdgcn_s_setprio(0);                                           \
  } while (0)

  // TILE: 4 phases; stages: p1 -> (s+1).A1, p2 -> (s+2).A0, p3 -> (s+2).B0,
  // p4 -> (s+2).B1. vmcnt(6) at p4 lands all of tile s+1.
#define TILE(s, P, DO_P1, DO_P234, VMSTMT) do {                              \
    READ_A(P, 0); READ_B(P, 0);                                              \
    if (DO_P1) STAGE_A((s) + 1, 1);                                          \
    BAR(); MFMA_Q(0, 0); BAR();                                              \
    READ_B(P, 1);                                                            \
    if (DO_P234) STAGE_A((s) + 2, 0);                                        \
    BAR(); MFMA_Q(0, 1); BAR();                                              \
    READ_A(P, 1);                                                            \
    if (DO_P234) STAGE_B((s) + 2, 0);                                        \
    BAR(); MFMA_Q(1, 0); BAR();                                              \
    if (DO_P234) STAGE_B((s) + 2, 1);                                        \
    BAR(); MFMA_Q(1, 1);                                                     \
    VMSTMT; BAR();                                                           \
  } while (0)

  // prologue: tile0 fully + tile1 {A0,B0,B1}; tile1.A1 comes at s=0 p1
  STAGE_A(0, 0); STAGE_B(0, 0); STAGE_B(0, 1); STAGE_A(0, 1);
  STAGE_A(1, 0); STAGE_B(1, 0); STAGE_B(1, 1);
  VM(6); BAR();

  for (int s = 0; s < NTILE - 2; s += 2) {
    TILE(s, 0, 1, 1, VM(6));
    TILE((s) + 1, 1, 1, 1, VM(6));
  }
  TILE(NTILE - 2, 0, 1, 0, VM(0));   // stage 63.A1 only; drain
  TILE(NTILE - 1, 1, 0, 0, (void)0);

  // epilogue: fused NF4 bias + non-temporal C stores
  // 32x32 C/D: col = lane&31, row = (reg&3) + 8*(reg>>2) + 4*hi
  float bias[2];
#pragma unroll
  for (int nq = 0; nq < 2; ++nq) {
    int col = (int)n0 + wc * 64 + nq * 32 + r32;
    int byte = bp[col >> 1];
    int code = (col & 1) ? (byte & 15) : ((byte >> 4) & 15);
    bias[nq] = NF4_TAB[code] * ba[col >> 6];
  }
#pragma unroll
  for (int mi = 0; mi < 4; ++mi) {
    size_t rowb = m0 + wr * 128 + mi * 32 + 4 * hi;
#pragma unroll
    for (int nq = 0; nq < 2; ++nq) {
      size_t col = n0 + wc * 64 + nq * 32 + r32;
#pragma unroll
      for (int g = 0; g < 4; ++g)
#pragma unroll
        for (int j = 0; j < 4; ++j)
          __builtin_nontemporal_store(
              acc[mi][nq][g * 4 + j] + bias[nq],
              &C[(rowb + g * 8 + j) * N + col]);
    }
  }
#undef TILE
#undef MFMA_Q
#undef READ_B
#undef READ_A
#undef STAGE_B
#undef STAGE_A
#undef VM
#undef BAR
#undef FENCE
}

extern "C" void kernel_launch(void* const* d_in, const int* in_sizes, int n_in,
                              void* d_out, int out_size, void* d_ws,
                              size_t ws_size, hipStream_t stream) {
  const float* x  = (const float*)d_in[0];
  const int* wp   = (const int*)d_in[1];
  const float* wa = (const float*)d_in[2];
  const int* bp   = (const int*)d_in[3];
  const float* ba = (const float*)d_in[4];
  float* out = (float*)d_out;

  u16* Wb = (u16*)d_ws;                     // [N][K] bf16
  u16* Xb = Wb + (size_t)N_OUT * K_IN;      // [M][K] bf16

  dequant_w_kernel<<<28672, 256, 0, stream>>>(wp, wa, Wb);
  convert_x_kernel<<<16384, 256, 0, stream>>>(x, Xb);

  hipFuncSetAttribute(reinterpret_cast<const void*>(gemm_nf4_256),
                      hipFuncAttributeMaxDynamicSharedMemorySize, 131072);
  // 32 m-tiles x 56 n-tiles
  gemm_nf4_256<<<1792, 512, 131072, stream>>>(Xb, Wb, out, bp, ba);
}

// Round 5
// 993.333 us; speedup vs baseline: 1.0003x; 1.0003x over previous
//
#include <hip/hip_runtime.h>

typedef unsigned short u16;
typedef __attribute__((ext_vector_type(8))) short bf16x8;
typedef __attribute__((ext_vector_type(4))) float f32x4;
typedef __attribute__((ext_vector_type(16))) float f32x16;
typedef __attribute__((ext_vector_type(4))) int i32x4;

#define M_ROWS 8192
#define N_OUT  14336
#define K_IN   4096
#define NTILE  64   // K_IN / 64

__constant__ float NF4_TAB[16] = {
    -1.0f, -0.6961928009986877f, -0.5250730514526367f, -0.39491748809814453f,
    -0.28444138169288635f, -0.18477343022823334f, -0.09105003625154495f, 0.0f,
    0.07958029955625534f, 0.16093020141124725f, 0.24611230194568634f,
    0.33791524171829224f, 0.44070982933044434f, 0.5626170039176941f,
    0.7229568362236023f, 1.0f};

static __device__ __forceinline__ u16 f2bf(float f) {
  union { float f; unsigned u; } v;
  v.f = f;
  unsigned u = v.u;
  unsigned r = (u + 0x7fffu + ((u >> 16) & 1u)) >> 16;
  return (u16)r;
}

static __device__ __forceinline__ void async_load16(const void* g, void* l) {
  __builtin_amdgcn_global_load_lds(
      (const __attribute__((address_space(1))) void*)g,
      (__attribute__((address_space(3))) void*)l, 16, 0, 0);
}

// ---------------------------------------------------------------------------
// Dequant W: 4 packed int32 / thread -> 8 bf16 (one 16B store)
// ---------------------------------------------------------------------------
__global__ __launch_bounds__(256) void dequant_w_kernel(
    const int* __restrict__ wp, const float* __restrict__ wa,
    u16* __restrict__ wout) {
  int t = blockIdx.x * 256 + threadIdx.x;
  const i32x4 p = __builtin_nontemporal_load(
      reinterpret_cast<const i32x4*>(wp) + t);
  float am = wa[t >> 3];
  int v[4] = {p.x, p.y, p.z, p.w};
  union { u16 us[8]; i32x4 v4; } o;
#pragma unroll
  for (int j = 0; j < 4; ++j) {
    o.us[2 * j]     = f2bf(NF4_TAB[(v[j] >> 4) & 15] * am);
    o.us[2 * j + 1] = f2bf(NF4_TAB[v[j] & 15] * am);
  }
  reinterpret_cast<i32x4*>(wout)[t] = o.v4;
}

// ---------------------------------------------------------------------------
// Convert X fp32 -> bf16, 8 elements/thread
// ---------------------------------------------------------------------------
__global__ __launch_bounds__(256) void convert_x_kernel(
    const float* __restrict__ x, u16* __restrict__ xb) {
  int t = blockIdx.x * 256 + threadIdx.x;
  const f32x4 a = __builtin_nontemporal_load(
      reinterpret_cast<const f32x4*>(x) + 2 * t);
  const f32x4 b = __builtin_nontemporal_load(
      reinterpret_cast<const f32x4*>(x) + 2 * t + 1);
  union { u16 us[8]; i32x4 v4; } o;
  o.us[0] = f2bf(a.x); o.us[1] = f2bf(a.y);
  o.us[2] = f2bf(a.z); o.us[3] = f2bf(a.w);
  o.us[4] = f2bf(b.x); o.us[5] = f2bf(b.y);
  o.us[6] = f2bf(b.z); o.us[7] = f2bf(b.w);
  reinterpret_cast<i32x4*>(xb)[t] = o.v4;
}

// ---------------------------------------------------------------------------
// 256x256x64 8-phase pipelined NT GEMM, 32x32x16 MFMA.
// A[M][K], B[N][K] bf16; C[M][N] fp32 + NF4 bias, non-temporal C stores.
// LDS: 2 buffers x (A 256x64 + B 256x64) bf16 = 128 KiB (dynamic).
// Swizzle involution g(r) = (r&7) ^ (((r>>3)&3)<<1); LDS[r][c] holds global
// chunk c ^ g(r). Read chunk for lane (v=lane&31, hi=lane>>5, k-step ks):
// (2ks+hi) ^ (v&7) ^ ((v>>3)<<1) -> full 8-chunk permutation under both
// consecutive-octet and strided-octet lane groupings (fixes R4's 4-way).
// ---------------------------------------------------------------------------
__global__ __launch_bounds__(512, 2) void gemm_nf4_256(
    const u16* __restrict__ A, const u16* __restrict__ B,
    float* __restrict__ C, const int* __restrict__ bp,
    const float* __restrict__ ba) {
  constexpr int K = K_IN, N = N_OUT;
  extern __shared__ u16 smem[];
  u16* sA = smem;            // [2][256][64]
  u16* sB = smem + 32768;    // [2][256][64]

  const int tid = threadIdx.x;
  const int w = tid >> 6, lane = tid & 63;
  const int r32 = lane & 31, hi = lane >> 5;
  const int wr = w >> 2, wc = w & 3;       // 2 x 4 wave grid

  // bijective XCD swizzle (1792 % 8 == 0): contiguous 224-wg chunk per XCD
  int bid = blockIdx.x;
  int cpx = gridDim.x >> 3;
  int wg = (bid & 7) * cpx + (bid >> 3);
  // mt-inner-8 supertile (L2 locality on B panels)
  int grp = wg / 448;                  // 448 = 56*8
  int rem = wg - grp * 448;
  int nt = rem >> 3;
  int mt = grp * 8 + (rem & 7);
  const size_t m0 = (size_t)mt * 256, n0 = (size_t)nt * 256;

  const u16* gA = A + m0 * K;
  const u16* gB = B + n0 * K;

  // read-side swizzled chunk offsets (u16 units), one per 16-wide k-step
  const int gmask = (r32 & 7) ^ ((r32 >> 3) << 1);
  int cswz[4];
#pragma unroll
  for (int ks = 0; ks < 4; ++ks)
    cswz[ks] = ((ks * 2 + hi) ^ gmask) * 8;
  // stage-side per-lane global chunk (involution partner); (R0>>3)&3 == w&3
  // for every STAGE_A/STAGE_B window (verified), row&7 == lane>>3.
  const int cg = (((lane & 7) ^ (lane >> 3) ^ ((w & 3) << 1)) & 7) * 8;
  const int jlane = lane >> 3;

  f32x16 acc[4][2] = {};       // [m-tile 32][n-tile 32] accumulators
  bf16x8 aF[2][4];             // [m-tile within quadrant][k-step]
  bf16x8 bF[2][4];             // [n-quadrant][k-step]

#define FENCE() asm volatile("" ::: "memory")
#define BAR() do { __builtin_amdgcn_s_barrier(); FENCE(); } while (0)
#define VM(n) asm volatile("s_waitcnt vmcnt(" #n ")" ::: "memory")

#define STAGE_A(u, mq) do {                                                  \
    int P_ = (u) & 1;                                                        \
    _Pragma("unroll")                                                        \
    for (int i_ = 0; i_ < 2; ++i_) {                                         \
      int j0_ = (i_ * 8 + w) * 8;                                            \
      int R0_ = (mq) * 64 + ((j0_ >> 6) << 7) + (j0_ & 63);                  \
      int R_ = R0_ + jlane;                                                  \
      async_load16(gA + (size_t)R_ * K + (u) * 64 + cg,                      \
                   sA + P_ * 16384 + R0_ * 64);                              \
    } } while (0)

#define STAGE_B(u, nq) do {                                                  \
    int P_ = (u) & 1;                                                        \
    _Pragma("unroll")                                                        \
    for (int i_ = 0; i_ < 2; ++i_) {                                         \
      int j0_ = (i_ * 8 + w) * 8;                                            \
      int R0_ = (nq) * 32 + ((j0_ >> 5) << 6) + (j0_ & 31);                  \
      int R_ = R0_ + jlane;                                                  \
      async_load16(gB + (size_t)R_ * K + (u) * 64 + cg,                      \
                   sB + P_ * 16384 + R0_ * 64);                              \
    } } while (0)

  // A-fragments for quadrant mq: rows wr*128 + mq*64 + t_*32 + r32
#define READ_A(P, mq) do {                                                   \
    const u16* pa_ = sA + (P) * 16384 + (wr * 128 + (mq) * 64 + r32) * 64;   \
    _Pragma("unroll")                                                        \
    for (int t_ = 0; t_ < 2; ++t_)                                           \
      _Pragma("unroll")                                                      \
      for (int ks_ = 0; ks_ < 4; ++ks_)                                      \
        aF[t_][ks_] = *(const bf16x8*)(pa_ + t_ * 2048 + cswz[ks_]);         \
    } while (0)

  // B-fragments for quadrant nq: rows wc*64 + nq*32 + r32
#define READ_B(P, nq) do {                                                   \
    const u16* pb_ = sB + (P) * 16384 + (wc * 64 + (nq) * 32 + r32) * 64;    \
    _Pragma("unroll")                                                        \
    for (int ks_ = 0; ks_ < 4; ++ks_)                                        \
      bF[(nq)][ks_] = *(const bf16x8*)(pb_ + cswz[ks_]);                     \
    } while (0)

#define MFMA_Q(mq, nq) do {                                                  \
    __builtin_amdgcn_s_setprio(1);                                           \
    _Pragma("unroll")                                                        \
    for (int ks_ = 0; ks_ < 4; ++ks_)                                        \
      _Pragma("unroll")                                                      \
      for (int t_ = 0; t_ < 2; ++t_)                                         \
        acc[(mq) * 2 + t_][(nq)] =                                           \
            __builtin_amdgcn_mfma_f32_32x32x16_bf16(                         \
                aF[t_][ks_], bF[(nq)][ks_], acc[(mq) * 2 + t_][(nq)],        \
                0, 0, 0);                                                    \
    __builtin_amdgcn_s_setprio(0);                                           \
  } while (0)

  // TILE: 4 phases; stages: p1 -> (s+1).A1, p2 -> (s+2).A0, p3 -> (s+2).B0,
  // p4 -> (s+2).B1. vmcnt(6) at p4 lands all of tile s+1.
#define TILE(s, P, DO_P1, DO_P234, VMSTMT) do {                              \
    READ_A(P, 0); READ_B(P, 0);                                              \
    if (DO_P1) STAGE_A((s) + 1, 1);                                          \
    BAR(); MFMA_Q(0, 0); BAR();                                              \
    READ_B(P, 1);                                                            \
    if (DO_P234) STAGE_A((s) + 2, 0);                                        \
    BAR(); MFMA_Q(0, 1); BAR();                                              \
    READ_A(P, 1);                                                            \
    if (DO_P234) STAGE_B((s) + 2, 0);                                        \
    BAR(); MFMA_Q(1, 0); BAR();                                              \
    if (DO_P234) STAGE_B((s) + 2, 1);                                        \
    BAR(); MFMA_Q(1, 1);                                                     \
    VMSTMT; BAR();                                                           \
  } while (0)

  // prologue: tile0 fully + tile1 {A0,B0,B1}; tile1.A1 comes at s=0 p1
  STAGE_A(0, 0); STAGE_B(0, 0); STAGE_B(0, 1); STAGE_A(0, 1);
  STAGE_A(1, 0); STAGE_B(1, 0); STAGE_B(1, 1);
  VM(6); BAR();

  for (int s = 0; s < NTILE - 2; s += 2) {
    TILE(s, 0, 1, 1, VM(6));
    TILE((s) + 1, 1, 1, 1, VM(6));
  }
  TILE(NTILE - 2, 0, 1, 0, VM(0));   // stage 63.A1 only; drain
  TILE(NTILE - 1, 1, 0, 0, (void)0);

  // epilogue: fused NF4 bias + non-temporal C stores
  // 32x32 C/D: col = lane&31, row = (reg&3) + 8*(reg>>2) + 4*hi
  float bias[2];
#pragma unroll
  for (int nq = 0; nq < 2; ++nq) {
    int col = (int)n0 + wc * 64 + nq * 32 + r32;
    int byte = bp[col >> 1];
    int code = (col & 1) ? (byte & 15) : ((byte >> 4) & 15);
    bias[nq] = NF4_TAB[code] * ba[col >> 6];
  }
#pragma unroll
  for (int mi = 0; mi < 4; ++mi) {
    size_t rowb = m0 + wr * 128 + mi * 32 + 4 * hi;
#pragma unroll
    for (int nq = 0; nq < 2; ++nq) {
      size_t col = n0 + wc * 64 + nq * 32 + r32;
#pragma unroll
      for (int g = 0; g < 4; ++g)
#pragma unroll
        for (int j = 0; j < 4; ++j)
          __builtin_nontemporal_store(
              acc[mi][nq][g * 4 + j] + bias[nq],
              &C[(rowb + g * 8 + j) * N + col]);
    }
  }
#undef TILE
#undef MFMA_Q
#undef READ_B
#undef READ_A
#undef STAGE_B
#undef STAGE_A
#undef VM
#undef BAR
#undef FENCE
}

extern "C" void kernel_launch(void* const* d_in, const int* in_sizes, int n_in,
                              void* d_out, int out_size, void* d_ws,
                              size_t ws_size, hipStream_t stream) {
  const float* x  = (const float*)d_in[0];
  const int* wp   = (const int*)d_in[1];
  const float* wa = (const float*)d_in[2];
  const int* bp   = (const int*)d_in[3];
  const float* ba = (const float*)d_in[4];
  float* out = (float*)d_out;

  u16* Wb = (u16*)d_ws;                     // [N][K] bf16
  u16* Xb = Wb + (size_t)N_OUT * K_IN;      // [M][K] bf16

  dequant_w_kernel<<<28672, 256, 0, stream>>>(wp, wa, Wb);
  convert_x_kernel<<<16384, 256, 0, stream>>>(x, Xb);

  hipFuncSetAttribute(reinterpret_cast<const void*>(gemm_nf4_256),
                      hipFuncAttributeMaxDynamicSharedMemorySize, 131072);
  // 32 m-tiles x 56 n-tiles
  gemm_nf4_256<<<1792, 512, 131072, stream>>>(Xb, Wb, out, bp, ba);
}

// Round 6
// 856.819 us; speedup vs baseline: 1.1597x; 1.1593x over previous
//
#include <hip/hip_runtime.h>

typedef unsigned short u16;
typedef __attribute__((ext_vector_type(8))) short bf16x8;
typedef __attribute__((ext_vector_type(4))) float f32x4;
typedef __attribute__((ext_vector_type(4))) int i32x4;

#define M_ROWS 8192
#define N_OUT  14336
#define K_IN   4096
#define NTILE  64   // K_IN / 64

__constant__ float NF4_TAB[16] = {
    -1.0f, -0.6961928009986877f, -0.5250730514526367f, -0.39491748809814453f,
    -0.28444138169288635f, -0.18477343022823334f, -0.09105003625154495f, 0.0f,
    0.07958029955625534f, 0.16093020141124725f, 0.24611230194568634f,
    0.33791524171829224f, 0.44070982933044434f, 0.5626170039176941f,
    0.7229568362236023f, 1.0f};

static __device__ __forceinline__ u16 f2bf(float f) {
  union { float f; unsigned u; } v;
  v.f = f;
  unsigned u = v.u;
  unsigned r = (u + 0x7fffu + ((u >> 16) & 1u)) >> 16;
  return (u16)r;
}

static __device__ __forceinline__ void async_load16(const void* g, void* l) {
  __builtin_amdgcn_global_load_lds(
      (const __attribute__((address_space(1))) void*)g,
      (__attribute__((address_space(3))) void*)l, 16, 0, 0);
}

// ---------------------------------------------------------------------------
// Dequant W: 4 packed int32 / thread -> 8 bf16 (one 16B store)
// ---------------------------------------------------------------------------
__global__ __launch_bounds__(256) void dequant_w_kernel(
    const int* __restrict__ wp, const float* __restrict__ wa,
    u16* __restrict__ wout) {
  int t = blockIdx.x * 256 + threadIdx.x;
  const i32x4 p = __builtin_nontemporal_load(
      reinterpret_cast<const i32x4*>(wp) + t);
  float am = wa[t >> 3];
  int v[4] = {p.x, p.y, p.z, p.w};
  union { u16 us[8]; i32x4 v4; } o;
#pragma unroll
  for (int j = 0; j < 4; ++j) {
    o.us[2 * j]     = f2bf(NF4_TAB[(v[j] >> 4) & 15] * am);
    o.us[2 * j + 1] = f2bf(NF4_TAB[v[j] & 15] * am);
  }
  reinterpret_cast<i32x4*>(wout)[t] = o.v4;
}

// ---------------------------------------------------------------------------
// Convert X fp32 -> bf16, 8 elements/thread
// ---------------------------------------------------------------------------
__global__ __launch_bounds__(256) void convert_x_kernel(
    const float* __restrict__ x, u16* __restrict__ xb) {
  int t = blockIdx.x * 256 + threadIdx.x;
  const f32x4 a = __builtin_nontemporal_load(
      reinterpret_cast<const f32x4*>(x) + 2 * t);
  const f32x4 b = __builtin_nontemporal_load(
      reinterpret_cast<const f32x4*>(x) + 2 * t + 1);
  union { u16 us[8]; i32x4 v4; } o;
  o.us[0] = f2bf(a.x); o.us[1] = f2bf(a.y);
  o.us[2] = f2bf(a.z); o.us[3] = f2bf(a.w);
  o.us[4] = f2bf(b.x); o.us[5] = f2bf(b.y);
  o.us[6] = f2bf(b.z); o.us[7] = f2bf(b.w);
  reinterpret_cast<i32x4*>(xb)[t] = o.v4;
}

// ---------------------------------------------------------------------------
// 256x256x64 8-phase pipelined NT GEMM, 16x16x32 MFMA (R3 structure).
// This round: NO compiler fences after barriers and NO explicit lgkmcnt --
// ds_reads are compiler-visible, so hipcc inserts fine-grained lgkmcnt and
// may hoist next-phase reads into the current MFMA window (s_barrier is
// IntrNoMem). Correctness anchors: (1) MFMA<-ds_read via dataflow; (2) reads
// and gload_lds cannot cross the VM(n) asm (memory clobber), preserving the
// per-tile landing guarantee and vmcnt positional semantics; (3) stages only
// target regions whose reads were consumed before the preceding post-MFMA
// barrier (double-barrier per phase).
// ---------------------------------------------------------------------------
__global__ __launch_bounds__(512, 2) void gemm_nf4_256(
    const u16* __restrict__ A, const u16* __restrict__ B,
    float* __restrict__ C, const int* __restrict__ bp,
    const float* __restrict__ ba) {
  constexpr int K = K_IN, N = N_OUT;
  extern __shared__ u16 smem[];
  u16* sA = smem;            // [2][256][64]
  u16* sB = smem + 32768;    // [2][256][64]

  const int tid = threadIdx.x;
  const int w = tid >> 6, lane = tid & 63;
  const int r = lane & 15, kq = lane >> 4;
  const int wr = w >> 2, wc = w & 3;       // 2 x 4 wave grid

  // bijective XCD swizzle (1792 % 8 == 0): contiguous 224-wg chunk per XCD
  int bid = blockIdx.x;
  int cpx = gridDim.x >> 3;
  int wg = (bid & 7) * cpx + (bid >> 3);
  // mt-inner-8 supertile (L2 locality on B panels)
  int grp = wg / 448;                  // 448 = 56*8
  int rem = wg - grp * 448;
  int nt = rem >> 3;
  int mt = grp * 8 + (rem & 7);
  const size_t m0 = (size_t)mt * 256, n0 = (size_t)nt * 256;

  const u16* gA = A + m0 * K;
  const u16* gB = B + n0 * K;

  // read-side swizzled chunk offsets (u16 units) for k-half 0/1
  const int cswz0 = ((kq) ^ (r & 7)) * 8;
  const int cswz1 = ((4 + kq) ^ (r & 7)) * 8;
  // stage-side per-lane global chunk (involution partner of the above)
  const int cg = ((lane & 7) ^ (lane >> 3)) * 8;
  const int jlane = lane >> 3;

  f32x4 acc[8][4] = {};
  bf16x8 aF[4][2], bF[4][2];

#define BAR() __builtin_amdgcn_s_barrier()
#define VM(n) asm volatile("s_waitcnt vmcnt(" #n ")" ::: "memory")

#define STAGE_A(u, mq) do {                                                  \
    int P_ = (u) & 1;                                                        \
    _Pragma("unroll")                                                        \
    for (int i_ = 0; i_ < 2; ++i_) {                                         \
      int j0_ = (i_ * 8 + w) * 8;                                            \
      int R0_ = (mq) * 64 + ((j0_ >> 6) << 7) + (j0_ & 63);                  \
      int R_ = R0_ + jlane;                                                  \
      async_load16(gA + (size_t)R_ * K + (u) * 64 + cg,                      \
                   sA + P_ * 16384 + R0_ * 64);                              \
    } } while (0)

#define STAGE_B(u, nq) do {                                                  \
    int P_ = (u) & 1;                                                        \
    _Pragma("unroll")                                                        \
    for (int i_ = 0; i_ < 2; ++i_) {                                         \
      int j0_ = (i_ * 8 + w) * 8;                                            \
      int R0_ = (nq) * 32 + ((j0_ >> 5) << 6) + (j0_ & 31);                  \
      int R_ = R0_ + jlane;                                                  \
      async_load16(gB + (size_t)R_ * K + (u) * 64 + cg,                      \
                   sB + P_ * 16384 + R0_ * 64);                              \
    } } while (0)

#define READ_A(P, mq) do {                                                   \
    const u16* ba_ = sA + (P) * 16384 + (wr * 128 + (mq) * 64 + r) * 64;     \
    _Pragma("unroll")                                                        \
    for (int m_ = 0; m_ < 4; ++m_) {                                         \
      aF[m_][0] = *(const bf16x8*)(ba_ + m_ * 1024 + cswz0);                 \
      aF[m_][1] = *(const bf16x8*)(ba_ + m_ * 1024 + cswz1);                 \
    } } while (0)

#define READ_B(P, nq) do {                                                   \
    const u16* bb_ = sB + (P) * 16384 + (wc * 64 + (nq) * 32 + r) * 64;      \
    _Pragma("unroll")                                                        \
    for (int n_ = 0; n_ < 2; ++n_) {                                         \
      bF[(nq) * 2 + n_][0] = *(const bf16x8*)(bb_ + n_ * 1024 + cswz0);      \
      bF[(nq) * 2 + n_][1] = *(const bf16x8*)(bb_ + n_ * 1024 + cswz1);      \
    } } while (0)

#define MFMA_Q(mq, nq) do {                                                  \
    __builtin_amdgcn_s_setprio(1);                                           \
    _Pragma("unroll")                                                        \
    for (int m_ = 0; m_ < 4; ++m_)                                           \
      _Pragma("unroll")                                                      \
      for (int n_ = 0; n_ < 2; ++n_) {                                       \
        acc[(mq) * 4 + m_][(nq) * 2 + n_] =                                  \
            __builtin_amdgcn_mfma_f32_16x16x32_bf16(                         \
                aF[m_][0], bF[(nq) * 2 + n_][0],                             \
                acc[(mq) * 4 + m_][(nq) * 2 + n_], 0, 0, 0);                 \
        acc[(mq) * 4 + m_][(nq) * 2 + n_] =                                  \
            __builtin_amdgcn_mfma_f32_16x16x32_bf16(                         \
                aF[m_][1], bF[(nq) * 2 + n_][1],                             \
                acc[(mq) * 4 + m_][(nq) * 2 + n_], 0, 0, 0);                 \
      }                                                                      \
    __builtin_amdgcn_s_setprio(0);                                           \
  } while (0)

  // TILE: 4 phases; stages: p1 -> (s+1).A1, p2 -> (s+2).A0, p3 -> (s+2).B0,
  // p4 -> (s+2).B1. vmcnt(6) at p4 lands all of tile s+1.
#define TILE(s, P, DO_P1, DO_P234, VMSTMT) do {                              \
    READ_A(P, 0); READ_B(P, 0);                                              \
    if (DO_P1) STAGE_A((s) + 1, 1);                                          \
    BAR(); MFMA_Q(0, 0); BAR();                                              \
    READ_B(P, 1);                                                            \
    if (DO_P234) STAGE_A((s) + 2, 0);                                        \
    BAR(); MFMA_Q(0, 1); BAR();                                              \
    READ_A(P, 1);                                                            \
    if (DO_P234) STAGE_B((s) + 2, 0);                                        \
    BAR(); MFMA_Q(1, 0); BAR();                                              \
    if (DO_P234) STAGE_B((s) + 2, 1);                                        \
    BAR(); MFMA_Q(1, 1);                                                     \
    VMSTMT; BAR();                                                           \
  } while (0)

  // prologue: tile0 fully + tile1 {A0,B0,B1}; tile1.A1 comes at s=0 p1
  STAGE_A(0, 0); STAGE_B(0, 0); STAGE_B(0, 1); STAGE_A(0, 1);
  STAGE_A(1, 0); STAGE_B(1, 0); STAGE_B(1, 1);
  VM(6); BAR();

  for (int s = 0; s < NTILE - 2; s += 2) {
    TILE(s, 0, 1, 1, VM(6));
    TILE((s) + 1, 1, 1, 1, VM(6));
  }
  TILE(NTILE - 2, 0, 1, 0, VM(0));   // stage 63.A1 only; drain
  TILE(NTILE - 1, 1, 0, 0, (void)0);

  // epilogue: fused NF4 bias + non-temporal C stores
  // (C/D: col=lane&15, row=(lane>>4)*4+j)
  float bias[4];
#pragma unroll
  for (int ni = 0; ni < 4; ++ni) {
    int col = (int)n0 + wc * 64 + ni * 16 + r;
    int byte = bp[col >> 1];
    int code = (col & 1) ? (byte & 15) : ((byte >> 4) & 15);
    bias[ni] = NF4_TAB[code] * ba[col >> 6];
  }
#pragma unroll
  for (int mi = 0; mi < 8; ++mi) {
    size_t row0 = m0 + wr * 128 + mi * 16 + (lane >> 4) * 4;
#pragma unroll
    for (int ni = 0; ni < 4; ++ni) {
      size_t col = n0 + wc * 64 + ni * 16 + r;
#pragma unroll
      for (int j = 0; j < 4; ++j)
        __builtin_nontemporal_store(acc[mi][ni][j] + bias[ni],
                                    &C[(row0 + j) * N + col]);
    }
  }
#undef TILE
#undef MFMA_Q
#undef READ_B
#undef READ_A
#undef STAGE_B
#undef STAGE_A
#undef VM
#undef BAR
}

extern "C" void kernel_launch(void* const* d_in, const int* in_sizes, int n_in,
                              void* d_out, int out_size, void* d_ws,
                              size_t ws_size, hipStream_t stream) {
  const float* x  = (const float*)d_in[0];
  const int* wp   = (const int*)d_in[1];
  const float* wa = (const float*)d_in[2];
  const int* bp   = (const int*)d_in[3];
  const float* ba = (const float*)d_in[4];
  float* out = (float*)d_out;

  u16* Wb = (u16*)d_ws;                     // [N][K] bf16
  u16* Xb = Wb + (size_t)N_OUT * K_IN;      // [M][K] bf16

  dequant_w_kernel<<<28672, 256, 0, stream>>>(wp, wa, Wb);
  convert_x_kernel<<<16384, 256, 0, stream>>>(x, Xb);

  hipFuncSetAttribute(reinterpret_cast<const void*>(gemm_nf4_256),
                      hipFuncAttributeMaxDynamicSharedMemorySize, 131072);
  // 32 m-tiles x 56 n-tiles
  gemm_nf4_256<<<1792, 512, 131072, stream>>>(Xb, Wb, out, bp, ba);
}